// Round 18
// baseline (117.934 us; speedup 1.0000x reference)
//
#include <hip/hip_runtime.h>

// x: (B=4, C=64, H=512, W=512) fp32 -> 131072 independent rows of 512 cols.
// FIR: f[j] = sum_k a[k]*x[j-2+k] (SAME zero-pad), then IIR:
//   y[j] = f[j] - (v0*y[j-3] + v1*y[j-2] + v2*y[j-1]), zero initial state.
//
// R18: 8-cols-per-thread redesign to cross the 64-VGPR occupancy quantum
// (m69: waves/SIMD = 8 at <=64 VGPR, 4 at <=128; R16's 16-col state was in
// the 128 bin). wave = 1 row (64 segs x 8 cols); block = 4 rows.
//   loads : own 2 f4 (stride 32B -> 64B/line/instr, half the line-requests)
//   halo  : 4 shuffles (left 2, right 2 floats)
//   phase1: particular solution y_p over 8 cols (zero entry state)
//   scan  : 6-round Hillis-Steele affine scan over 64 segments; M^(2^rd)
//           precomputed by thread 0 into 216B LDS (broadcast reads ~free)
//   fixup : w[k] recursion from entering state (R13)
//   stores: 16-shuffle transpose -> 2 x 1KB contiguous (full-line) per wave

constexpr int Wd    = 512;
constexpr int TROWS = 4;        // rows per block (1 per wave)
constexpr int NT    = 256;
constexpr int F4ROW = Wd / 4;   // 128

__global__ __launch_bounds__(NT, 8)
void iir_conv2d_kernel(const float4* __restrict__ x4,
                       const float* __restrict__ w1,   // (C,1,5)
                       const float* __restrict__ w2,   // (C,3)
                       float4* __restrict__ y4)
{
    __shared__ float Mt[6][9];   // M^(2^rd), row-major [i*3+j]

    const int tid  = threadIdx.x;
    const int lane = tid & 63;
    const int wv   = tid >> 6;          // wave = row within block (0..3)
    const int s    = lane;              // 8-col segment (0..63)
    const int row0 = blockIdx.x * TROWS;   // 4 | 512 -> channel uniform per block
    const int row  = row0 + wv;
    const int c    = (row0 >> 9) & 63;

    // taps (block-uniform -> scalar loads)
    const float a0 = w1[c*5+0], a1 = w1[c*5+1], a2 = w1[c*5+2],
                a3 = w1[c*5+3], a4 = w1[c*5+4];
    const float v0 = w2[c*3+0], v1 = w2[c*3+1], v2 = w2[c*3+2];

    // ---- loads: this thread's 2 f4 (cols 8s..8s+7) ----
    const float4* __restrict__ xr = x4 + (size_t)row * F4ROW;
    float4 xv0 = xr[2*s+0], xv1 = xr[2*s+1];

    // ---- thread 0: M (8-step transform) and its 5 squarings into LDS ----
    if (tid == 0) {
        float h3a = 1.f, h2a = 0.f, h1a = 0.f;
        float h3b = 0.f, h2b = 1.f, h1b = 0.f;
        float h3c = 0.f, h2c = 0.f, h1c = 1.f;
        float P[9];
        #pragma unroll
        for (int k = 0; k < 8; ++k) {
            const float na = -(v0*h3a + v1*h2a + v2*h1a);
            const float nb = -(v0*h3b + v1*h2b + v2*h1b);
            const float nc = -(v0*h3c + v1*h2c + v2*h1c);
            if (k == 5) { P[0] = na; P[1] = nb; P[2] = nc; }
            if (k == 6) { P[3] = na; P[4] = nb; P[5] = nc; }
            if (k == 7) { P[6] = na; P[7] = nb; P[8] = nc; }
            h3a = h2a; h2a = h1a; h1a = na;
            h3b = h2b; h2b = h1b; h1b = nb;
            h3c = h2c; h2c = h1c; h1c = nc;
        }
        #pragma unroll
        for (int j = 0; j < 9; ++j) Mt[0][j] = P[j];
        #pragma unroll
        for (int rd = 1; rd < 6; ++rd) {
            float N[9];
            #pragma unroll
            for (int i = 0; i < 3; ++i)
                #pragma unroll
                for (int j = 0; j < 3; ++j)
                    N[3*i+j] = P[3*i+0]*P[0+j] + P[3*i+1]*P[3+j] + P[3*i+2]*P[6+j];
            #pragma unroll
            for (int j = 0; j < 9; ++j) { Mt[rd][j] = N[j]; P[j] = N[j]; }
        }
    }

    // ---- halo: cols 8s-2, 8s-1 from left lane's xv1.zw; 8s+8, 8s+9 from
    //      right lane's xv0.xy ----
    float xw[12];
    {
        const int srcL = (s >= 1)  ? (lane - 1) : lane;
        const int srcR = (s <= 62) ? (lane + 1) : lane;
        float l2 = __shfl(xv1.z, srcL, 64);
        float l3 = __shfl(xv1.w, srcL, 64);
        float r0 = __shfl(xv0.x, srcR, 64);
        float r1 = __shfl(xv0.y, srcR, 64);
        if (s == 0)  { l2 = 0.f; l3 = 0.f; }
        if (s == 63) { r0 = 0.f; r1 = 0.f; }
        xw[0] = l2; xw[1] = l3;
        xw[2] = xv0.x; xw[3] = xv0.y; xw[4]  = xv0.z; xw[5]  = xv0.w;
        xw[6] = xv1.x; xw[7] = xv1.y; xw[8]  = xv1.z; xw[9]  = xv1.w;
        xw[10] = r0; xw[11] = r1;
    }

    // ---- phase 1: particular solution (zero entry state) ----
    float y[8];
    {
        float ym3 = 0.f, ym2 = 0.f, ym1 = 0.f;
        #pragma unroll
        for (int k = 0; k < 8; ++k) {
            // col 8s+k needs x[col-2..col+2] = xw[k..k+4]
            const float f = a0*xw[k] + a1*xw[k+1] + a2*xw[k+2]
                          + a3*xw[k+3] + a4*xw[k+4];
            const float t = v0*ym3 + v1*ym2;      // off the serial chain
            const float yy = (f - t) - v2*ym1;
            y[k] = yy;
            ym3 = ym2; ym2 = ym1; ym1 = yy;
        }
    }

    __syncthreads();   // Mt ready (the only barrier)

    // ---- affine scan over 64 segments (full wave, 6 rounds) ----
    float b0 = y[5], b1 = y[6], b2 = y[7];
    #pragma unroll
    for (int rd = 0; rd < 6; ++rd) {
        const int d = 1 << rd;
        const float m00 = Mt[rd][0], m01 = Mt[rd][1], m02 = Mt[rd][2];
        const float m10 = Mt[rd][3], m11 = Mt[rd][4], m12 = Mt[rd][5];
        const float m20 = Mt[rd][6], m21 = Mt[rd][7], m22 = Mt[rd][8];
        const int src = (s >= d) ? (lane - d) : lane;
        const float g0 = __shfl(b0, src, 64);
        const float g1 = __shfl(b1, src, 64);
        const float g2 = __shfl(b2, src, 64);
        if (s >= d) {
            b0 += m00*g0 + m01*g1 + m02*g2;
            b1 += m10*g0 + m11*g1 + m12*g2;
            b2 += m20*g0 + m21*g1 + m22*g2;
        }
    }

    // ---- entering state = inclusive scan of previous segment; fixup ----
    {
        const int src = (s >= 1) ? (lane - 1) : lane;
        float wm3 = __shfl(b0, src, 64);
        float wm2 = __shfl(b1, src, 64);
        float wm1 = __shfl(b2, src, 64);
        if (s == 0) { wm3 = 0.f; wm2 = 0.f; wm1 = 0.f; }
        #pragma unroll
        for (int k = 0; k < 8; ++k) {
            const float w = -(v0*wm3 + v1*wm2 + v2*wm1);
            y[k] += w;
            wm3 = wm2; wm2 = wm1; wm1 = w;
        }
    }

    // ---- store: 16-shuffle transpose -> 2 x 1KB contiguous per wave ----
    // Instr u: lane i stores f4 g = 64u+i of its row; owner p = 32u+(i>>1),
    // reg q = i&1. q-loop keeps register indices compile-time.
    float4* __restrict__ yrow = y4 + (size_t)row * F4ROW;
    #pragma unroll
    for (int u = 0; u < 2; ++u) {
        const int srcl = 32*u + (lane >> 1);
        float out0, out1, out2, out3;
        #pragma unroll
        for (int q = 0; q < 2; ++q) {
            const float t0 = __shfl(y[4*q+0], srcl, 64);
            const float t1 = __shfl(y[4*q+1], srcl, 64);
            const float t2 = __shfl(y[4*q+2], srcl, 64);
            const float t3 = __shfl(y[4*q+3], srcl, 64);
            if ((lane & 1) == q) { out0 = t0; out1 = t1; out2 = t2; out3 = t3; }
        }
        float4 o; o.x = out0; o.y = out1; o.z = out2; o.w = out3;
        yrow[64*u + lane] = o;
    }
}

extern "C" void kernel_launch(void* const* d_in, const int* in_sizes, int n_in,
                              void* d_out, int out_size, void* d_ws, size_t ws_size,
                              hipStream_t stream) {
    const float4* x4 = (const float4*)d_in[0];
    const float*  w1 = (const float*)d_in[1];
    const float*  w2 = (const float*)d_in[2];
    float4* y4 = (float4*)d_out;

    const int nrows  = out_size / Wd;        // 131072
    const int blocks = nrows / TROWS;        // 32768
    iir_conv2d_kernel<<<blocks, NT, 0, stream>>>(x4, w1, w2, y4);
}